// Round 1
// 863.153 us; speedup vs baseline: 1.2027x; 1.2027x over previous
//
#include <hip/hip_runtime.h>

static constexpr int N  = 128;   // N_STATE
static constexpr int S  = 8192;  // SEQ
static constexpr int L  = 128;   // chunk length
static constexpr int NC = 64;    // S/L
static constexpr int OD = 1000;  // OUT_DIM
static constexpr int KSPLIT = 16;
#define SCL 0.25f                // 1/sqrt(D_HEAD=16)

typedef unsigned short u16;
typedef __attribute__((ext_vector_type(4))) unsigned short us4;
typedef __attribute__((ext_vector_type(8))) unsigned short us8;
typedef __attribute__((ext_vector_type(8))) short bf16x8;   // 8 bf16 = 4 VGPRs
typedef __attribute__((ext_vector_type(4))) float f32x4;

__device__ __forceinline__ u16 f2bf(float x){
  unsigned u = __float_as_uint(x);
  u += 0x7FFFu + ((u >> 16) & 1u);   // RNE to bf16
  return (u16)(u >> 16);
}
__device__ __forceinline__ float bf2f(u16 h){
  return __uint_as_float(((unsigned)h) << 16);
}

// ws layout (floats):
//  QT[0..128]: (GA^i)^T row-major                               129*16384
//  g[k][n] = (GA^k GB)[n]                                       128*128
//  bounds[j][s][n]                                              65*3*128
//  cs[s][t][n]  (q,k,v HiPPO states)                            3*8192*128
//  ctx[t][n]                                                    8192*128
//  qkh/qkl: bf16 hi/lo of q,k states [2][S][N]                  2*(S*N) floats
//  vth/vtl: bf16 hi/lo of v states TRANSPOSED [N][S]            2*(S*N/2) floats
//  part[kz][t][n]                                               16*8192*128

// ---- QT[1] = GA^T ----
__global__ void k_copyT(const float* __restrict__ GA, float* __restrict__ QT1){
  int idx = blockIdx.x*256 + threadIdx.x;
  int m = idx >> 7, n = idx & 127;
  QT1[idx] = GA[n*N + m];
}

// ---- QT[mlev+i] = QT[mlev] @ QT[i] ----
__global__ __launch_bounds__(256) void k_powmm(float* QT, int mlev){
  int i = blockIdx.z + 1;
  const float* Am = QT + (size_t)mlev*(N*N);
  const float* Ai = QT + (size_t)i*(N*N);
  float* C = QT + (size_t)(mlev+i)*(N*N);
  __shared__ __align__(16) float As[16][68];
  __shared__ __align__(16) float Bs[16][68];
  int bm = blockIdx.y, bn = blockIdx.x;
  int tx = threadIdx.x, ty = threadIdx.y;
  int tid = ty*16 + tx;
  float acc[4][4] = {};
  for (int kt = 0; kt < N; kt += 16){
    int row = tid >> 2, kc = (tid & 3) << 2;
    float4 av = *(const float4*)(Am + (size_t)(bm*64+row)*N + kt + kc);
    As[kc+0][row]=av.x; As[kc+1][row]=av.y; As[kc+2][row]=av.z; As[kc+3][row]=av.w;
    int bk = tid >> 4, c0 = (tid & 15) << 2;
    *(float4*)&Bs[bk][c0] = *(const float4*)(Ai + (size_t)(kt+bk)*N + bn*64 + c0);
    __syncthreads();
#pragma unroll
    for (int kk = 0; kk < 16; ++kk){
      float4 a = *(const float4*)&As[kk][ty*4];
      float4 b = *(const float4*)&Bs[kk][tx*4];
      float aa[4]={a.x,a.y,a.z,a.w}, bb[4]={b.x,b.y,b.z,b.w};
#pragma unroll
      for (int ii=0; ii<4; ++ii)
#pragma unroll
        for (int jj=0; jj<4; ++jj) acc[ii][jj] += aa[ii]*bb[jj];
    }
    __syncthreads();
  }
#pragma unroll
  for (int ii=0; ii<4; ++ii){
    float4 vst = make_float4(acc[ii][0],acc[ii][1],acc[ii][2],acc[ii][3]);
    *(float4*)(C + (size_t)(bm*64+ty*4+ii)*N + bn*64 + tx*4) = vst;
  }
}

// ---- g[k] = GA^k GB ----
__global__ void k_g(const float* __restrict__ QT, const float* __restrict__ GB,
                    float* __restrict__ g){
  int kb = blockIdx.x;
  int n = threadIdx.x;
  if (kb == 0){ g[n] = GB[n]; return; }
  const float* Qk = QT + (size_t)kb*(N*N);
  float acc = 0.0f;
  for (int m = 0; m < N; ++m) acc += Qk[m*N + n]*GB[m];
  g[kb*N + n] = acc;
}

// ---- within-chunk causal conv ----
__global__ __launch_bounds__(256) void k_fill_local(const float* __restrict__ fq,
                             const float* __restrict__ fk, const float* __restrict__ fv,
                             const float* __restrict__ g, float* __restrict__ cs){
  int tile = blockIdx.x;
  int s = blockIdx.y, j = blockIdx.z;
  const float* f = (s==0)? fq : (s==1)? fk : fv;
  __shared__ float flp[256];
  __shared__ __align__(16) float Bs[16][68];
  int tx = threadIdx.x, ty = threadIdx.y;
  int tid = ty*16 + tx;
  flp[tid] = (tid < 128) ? 0.0f : f[j*L + tid - 128];
  int ti = tile >> 1, tj = tile & 1;
  float acc[4][4] = {};
  int kmax = (ti == 0) ? 64 : 128;
  for (int kt = 0; kt < kmax; kt += 16){
    int bk = tid >> 4, c0 = (tid & 15) << 2;
    *(float4*)&Bs[bk][c0] = *(const float4*)(g + (size_t)(kt+bk)*N + tj*64 + c0);
    __syncthreads();
#pragma unroll
    for (int kk = 0; kk < 16; ++kk){
      float4 b = *(const float4*)&Bs[kk][tx*4];
      int base = 128 + ti*64 + ty*4 - kt - kk;
      float aa[4] = {flp[base], flp[base+1], flp[base+2], flp[base+3]};
      float bb[4] = {b.x, b.y, b.z, b.w};
#pragma unroll
      for (int ii=0; ii<4; ++ii)
#pragma unroll
        for (int jj=0; jj<4; ++jj) acc[ii][jj] += aa[ii]*bb[jj];
    }
    __syncthreads();
  }
#pragma unroll
  for (int ii=0; ii<4; ++ii){
    int row = ti*64 + ty*4 + ii;
    float4 vst = make_float4(acc[ii][0],acc[ii][1],acc[ii][2],acc[ii][3]);
    *(float4*)(cs + ((size_t)s*S + (size_t)j*L + row)*N + tj*64 + tx*4) = vst;
  }
}

// ---- sequential chunk-boundary scan ----
__global__ void k_bscan(const float* __restrict__ QT, const float* __restrict__ cs,
                        float* __restrict__ bounds){
  __shared__ float bc[3][N];
  __shared__ float bnx[3][N];
  int tid = threadIdx.x;
  int s = tid >> 7, n = tid & 127;
  const float* QL = QT + (size_t)L*(N*N);
  bc[s][n] = 0.0f;
  bounds[(0*3+s)*N + n] = 0.0f;
  __syncthreads();
  for (int j = 0; j < NC; ++j){
    float acc = cs[((size_t)s*S + (size_t)j*L + 127)*N + n];
    for (int m = 0; m < N; ++m) acc += QL[m*N+n]*bc[s][m];
    bnx[s][n] = acc;
    bounds[((j+1)*3+s)*N + n] = acc;
    __syncthreads();
    bc[s][n] = bnx[s][n];
    __syncthreads();
  }
}

// ---- boundary fill ----
__global__ __launch_bounds__(256) void k_fill_bound(const float* __restrict__ QT,
                          const float* __restrict__ bounds, float* __restrict__ cs){
  int i = blockIdx.x;
  int jg = blockIdx.y;
  __shared__ float Qs[N*N];
  int tid = threadIdx.x;
  int p = tid >> 7, n = tid & 127;
  const float* Qg = QT + (size_t)(i+1)*(N*N);
  for (int idx = tid; idx < N*N; idx += 256) Qs[idx] = Qg[idx];
  __syncthreads();
  for (int r = 0; r < 24; ++r){
    int task = jg*48 + p*24 + r;
    int j = task/3, s = task - 3*j;
    const float* b = bounds + (size_t)task*N;
    float a0=0.f, a1=0.f, a2=0.f, a3=0.f;
    for (int m = 0; m < N; m += 4){
      a0 += Qs[(m+0)*N+n]*b[m+0];
      a1 += Qs[(m+1)*N+n]*b[m+1];
      a2 += Qs[(m+2)*N+n]*b[m+2];
      a3 += Qs[(m+3)*N+n]*b[m+3];
    }
    cs[((size_t)s*S + (size_t)j*L + i)*N + n] += (a0+a1)+(a2+a3);
  }
}

// ---- split q,k states into bf16 hi/lo (natural [2*S][N] layout) ----
__global__ void k_split_qk(const float* __restrict__ cs,
                           u16* __restrict__ sh, u16* __restrict__ sl){
  size_t i = ((size_t)blockIdx.x*256 + threadIdx.x) << 2;   // over 2*S*N floats
  float4 v = *(const float4*)(cs + i);
  us4 h, l;
  h[0]=f2bf(v.x); l[0]=f2bf(v.x - bf2f(h[0]));
  h[1]=f2bf(v.y); l[1]=f2bf(v.y - bf2f(h[1]));
  h[2]=f2bf(v.z); l[2]=f2bf(v.z - bf2f(h[2]));
  h[3]=f2bf(v.w); l[3]=f2bf(v.w - bf2f(h[3]));
  *(us4*)(sh + i) = h;
  *(us4*)(sl + i) = l;
}

// ---- split v states into bf16 hi/lo, TRANSPOSED to [N][S] ----
__global__ __launch_bounds__(256) void k_split_vT(const float* __restrict__ vs,
                           u16* __restrict__ vth, u16* __restrict__ vtl){
  __shared__ u16 Th[128*72];   // [n][t-within-tile], pad stride 72
  __shared__ u16 Tl[128*72];
  int t0 = blockIdx.x * 64;
  int tid = threadIdx.x;
  for (int c = tid; c < 2048; c += 256){       // 64 t-rows * 32 float4 chunks
    int i = c >> 5, n0 = (c & 31) << 2;
    float4 v = *(const float4*)(vs + (size_t)(t0 + i)*N + n0);
    u16 h;
    h = f2bf(v.x); Th[(n0+0)*72 + i] = h; Tl[(n0+0)*72 + i] = f2bf(v.x - bf2f(h));
    h = f2bf(v.y); Th[(n0+1)*72 + i] = h; Tl[(n0+1)*72 + i] = f2bf(v.y - bf2f(h));
    h = f2bf(v.z); Th[(n0+2)*72 + i] = h; Tl[(n0+2)*72 + i] = f2bf(v.z - bf2f(h));
    h = f2bf(v.w); Th[(n0+3)*72 + i] = h; Tl[(n0+3)*72 + i] = f2bf(v.w - bf2f(h));
  }
  __syncthreads();
  for (int c = tid; c < 1024; c += 256){       // 128 n-rows * 8 chunks of 8
    int n = c >> 3, tc = (c & 7) << 3;
    *(us8*)(vth + (size_t)n*S + t0 + tc) = *(const us8*)&Th[n*72 + tc];
    *(us8*)(vtl + (size_t)n*S + t0 + tc) = *(const us8*)&Tl[n*72 + tc];
  }
}

// ---- scores via split-bf16 MFMA: attn = 0.25 * q @ k^T ----
// C = (Qh+Ql)(Kh+Kl)^T ~= Qh Kh^T + Qh Kl^T + Ql Kh^T   (drop l*l, ~2^-16 rel)
__global__ __launch_bounds__(256) void k_score_mfma(
    const u16* __restrict__ qh, const u16* __restrict__ ql,
    const u16* __restrict__ kh, const u16* __restrict__ kl,
    float* __restrict__ attn){
  __shared__ u16 Ah[128*40], Al[128*40], Bh[128*40], Bl[128*40];  // pad 40 -> 2-way bank only
  int bm = blockIdx.y, bn = blockIdx.x;
  int tid = threadIdx.x;
  int lane = tid & 63, w = tid >> 6;
  int wr = w >> 1, wc = w & 1;            // wave -> 64x64 sub-tile
  f32x4 acc[4][4] = {};
  int rA = wr*64 + (lane & 15);
  int rB = wc*64 + (lane & 15);
  int kg = (lane >> 4) << 3;
  for (int kt = 0; kt < N; kt += 32){
    for (int c = tid; c < 512; c += 256){  // 128 rows * 4 chunks of 8 bf16
      int r = c >> 2, k8 = (c & 3) << 3;
      size_t ga = (size_t)(bm*128 + r)*N + kt + k8;
      size_t gb = (size_t)(bn*128 + r)*N + kt + k8;
      int lo = r*40 + k8;
      *(us8*)&Ah[lo] = *(const us8*)(qh + ga);
      *(us8*)&Al[lo] = *(const us8*)(ql + ga);
      *(us8*)&Bh[lo] = *(const us8*)(kh + gb);
      *(us8*)&Bl[lo] = *(const us8*)(kl + gb);
    }
    __syncthreads();
    bf16x8 ah[4], al[4], bh[4], bl[4];
#pragma unroll
    for (int mi = 0; mi < 4; ++mi){
      ah[mi] = *(const bf16x8*)&Ah[(rA + mi*16)*40 + kg];
      al[mi] = *(const bf16x8*)&Al[(rA + mi*16)*40 + kg];
    }
#pragma unroll
    for (int ni = 0; ni < 4; ++ni){
      bh[ni] = *(const bf16x8*)&Bh[(rB + ni*16)*40 + kg];
      bl[ni] = *(const bf16x8*)&Bl[(rB + ni*16)*40 + kg];
    }
#pragma unroll
    for (int mi = 0; mi < 4; ++mi)
#pragma unroll
      for (int ni = 0; ni < 4; ++ni){
        acc[mi][ni] = __builtin_amdgcn_mfma_f32_16x16x32_bf16(ah[mi], bh[ni], acc[mi][ni], 0,0,0);
        acc[mi][ni] = __builtin_amdgcn_mfma_f32_16x16x32_bf16(ah[mi], bl[ni], acc[mi][ni], 0,0,0);
        acc[mi][ni] = __builtin_amdgcn_mfma_f32_16x16x32_bf16(al[mi], bh[ni], acc[mi][ni], 0,0,0);
      }
    __syncthreads();
  }
  // C mapping: col = lane&15, row = (lane>>4)*4 + reg   [m89-verified]
  int r0 = bm*128 + wr*64 + ((lane >> 4) << 2);
  int c0 = bn*128 + wc*64 + (lane & 15);
#pragma unroll
  for (int mi = 0; mi < 4; ++mi)
#pragma unroll
    for (int ni = 0; ni < 4; ++ni)
#pragma unroll
      for (int r = 0; r < 4; ++r)
        attn[(size_t)(r0 + mi*16 + r)*S + c0 + ni*16] = acc[mi][ni][r] * SCL;
}

// ---- exact row softmax in place ----
__global__ __launch_bounds__(256) void k_softmax(float* __restrict__ attn){
  __shared__ __align__(16) float rowb[S];
  __shared__ float red[256];
  int t = blockIdx.x;
  int tid = threadIdx.x;
  float4* g4 = (float4*)(attn + (size_t)t*S);
  float4* r4 = (float4*)rowb;
  float mx = -3.0e38f;
  for (int u = tid; u < S/4; u += 256){
    float4 v = g4[u];
    r4[u] = v;
    mx = fmaxf(mx, fmaxf(fmaxf(v.x,v.y), fmaxf(v.z,v.w)));
  }
  red[tid] = mx; __syncthreads();
  for (int st = 128; st > 0; st >>= 1){
    if (tid < st) red[tid] = fmaxf(red[tid], red[tid+st]);
    __syncthreads();
  }
  mx = red[0];
  __syncthreads();
  float sum = 0.0f;
  for (int u = tid; u < S/4; u += 256){
    float4 v = r4[u];
    v.x = __expf(v.x - mx); v.y = __expf(v.y - mx);
    v.z = __expf(v.z - mx); v.w = __expf(v.w - mx);
    r4[u] = v;
    sum += v.x + v.y + v.z + v.w;
  }
  red[tid] = sum; __syncthreads();
  for (int st = 128; st > 0; st >>= 1){
    if (tid < st) red[tid] += red[tid+st];
    __syncthreads();
  }
  float inv = 1.0f / red[0];
  for (int u = tid; u < S/4; u += 256){
    float4 v = r4[u];
    v.x *= inv; v.y *= inv; v.z *= inv; v.w *= inv;
    g4[u] = v;
  }
}

// ---- context via split-bf16 MFMA: part[kz] = attn[:,kz] @ v[kz,:] ----
// attn converted fp32 -> bf16 hi/lo in-LDS during staging (each elem once).
__global__ __launch_bounds__(256) void k_context_mfma(const float* __restrict__ attn,
                       const u16* __restrict__ vth, const u16* __restrict__ vtl,
                       float* __restrict__ dst, int mode){
  __shared__ u16 Ah[128*40], Al[128*40], Bh[128*40], Bl[128*40];
  int kz = blockIdx.x, bm = blockIdx.y;
  int tid = threadIdx.x;
  int lane = tid & 63, w = tid >> 6;
  int wr = w >> 1, wc = w & 1;
  const int KC = S / KSPLIT;   // 512
  int k0 = kz*KC;
  f32x4 acc[4][4] = {};
  int rA = wr*64 + (lane & 15);
  int rB = wc*64 + (lane & 15);
  int kg = (lane >> 4) << 3;
  for (int kt = 0; kt < KC; kt += 32){
    for (int c = tid; c < 1024; c += 256){     // attn tile 128x32 fp32 -> hi/lo
      int r = c >> 3, c4 = (c & 7) << 2;
      float4 v = *(const float4*)(attn + (size_t)(bm*128 + r)*S + k0 + kt + c4);
      us4 h, l;
      h[0]=f2bf(v.x); l[0]=f2bf(v.x - bf2f(h[0]));
      h[1]=f2bf(v.y); l[1]=f2bf(v.y - bf2f(h[1]));
      h[2]=f2bf(v.z); l[2]=f2bf(v.z - bf2f(h[2]));
      h[3]=f2bf(v.w); l[3]=f2bf(v.w - bf2f(h[3]));
      int lo = r*40 + c4;
      *(us4*)&Ah[lo] = h;
      *(us4*)&Al[lo] = l;
    }
    for (int c = tid; c < 512; c += 256){      // vT tile 128x32 bf16 hi/lo
      int n = c >> 2, k8 = (c & 3) << 3;
      size_t gb = (size_t)n*S + k0 + kt + k8;
      int lo = n*40 + k8;
      *(us8*)&Bh[lo] = *(const us8*)(vth + gb);
      *(us8*)&Bl[lo] = *(const us8*)(vtl + gb);
    }
    __syncthreads();
    bf16x8 ah[4], al[4], bh[4], bl[4];
#pragma unroll
    for (int mi = 0; mi < 4; ++mi){
      ah[mi] = *(const bf16x8*)&Ah[(rA + mi*16)*40 + kg];
      al[mi] = *(const bf16x8*)&Al[(rA + mi*16)*40 + kg];
    }
#pragma unroll
    for (int ni = 0; ni < 4; ++ni){
      bh[ni] = *(const bf16x8*)&Bh[(rB + ni*16)*40 + kg];
      bl[ni] = *(const bf16x8*)&Bl[(rB + ni*16)*40 + kg];
    }
#pragma unroll
    for (int mi = 0; mi < 4; ++mi)
#pragma unroll
      for (int ni = 0; ni < 4; ++ni){
        acc[mi][ni] = __builtin_amdgcn_mfma_f32_16x16x32_bf16(ah[mi], bh[ni], acc[mi][ni], 0,0,0);
        acc[mi][ni] = __builtin_amdgcn_mfma_f32_16x16x32_bf16(ah[mi], bl[ni], acc[mi][ni], 0,0,0);
        acc[mi][ni] = __builtin_amdgcn_mfma_f32_16x16x32_bf16(al[mi], bh[ni], acc[mi][ni], 0,0,0);
      }
    __syncthreads();
  }
  int r0 = bm*128 + wr*64 + ((lane >> 4) << 2);
  int c0 = wc*64 + (lane & 15);
  if (mode == 0){
    float* P = dst + (size_t)kz*S*N;
#pragma unroll
    for (int mi = 0; mi < 4; ++mi)
#pragma unroll
      for (int ni = 0; ni < 4; ++ni)
#pragma unroll
        for (int r = 0; r < 4; ++r)
          P[(size_t)(r0 + mi*16 + r)*N + c0 + ni*16] = acc[mi][ni][r];
  } else {
#pragma unroll
    for (int mi = 0; mi < 4; ++mi)
#pragma unroll
      for (int ni = 0; ni < 4; ++ni)
#pragma unroll
        for (int r = 0; r < 4; ++r)
          atomicAdd(&dst[(size_t)(r0 + mi*16 + r)*N + c0 + ni*16], acc[mi][ni][r]);
  }
}

// ---- reduce partials -> ctx ----
__global__ __launch_bounds__(256) void k_reduce(const float* __restrict__ part,
                                                float* __restrict__ ctx){
  size_t idx = (size_t)blockIdx.x*256 + threadIdx.x;
  const float4* p4 = (const float4*)part;
  float4 acc = p4[idx];
  const size_t stride = (size_t)S*N/4;
#pragma unroll
  for (int kz = 1; kz < KSPLIT; ++kz){
    float4 v = p4[(size_t)kz*stride + idx];
    acc.x += v.x; acc.y += v.y; acc.z += v.z; acc.w += v.w;
  }
  ((float4*)ctx)[idx] = acc;
}

// ---- out = ctx @ Wp + bp ----
__global__ __launch_bounds__(256) void k_out(const float* __restrict__ ctx,
                   const float* __restrict__ Wp, const float* __restrict__ bp,
                   float* __restrict__ out){
  __shared__ __align__(16) float As[16][68];
  __shared__ __align__(16) float Bs[16][68];
  int bn = blockIdx.x;
  int bm = blockIdx.y;
  int tx = threadIdx.x, ty = threadIdx.y;
  int tid = ty*16 + tx;
  float acc[4][4] = {};
  for (int kt = 0; kt < N; kt += 16){
    int row = tid >> 2, kc = (tid & 3) << 2;
    float4 av = *(const float4*)(ctx + (size_t)(bm*64+row)*N + kt + kc);
    As[kc+0][row]=av.x; As[kc+1][row]=av.y; As[kc+2][row]=av.z; As[kc+3][row]=av.w;
    int bk = tid >> 4, c0 = (tid & 15) << 2;
#pragma unroll
    for (int jj = 0; jj < 4; ++jj){
      int c = bn*64 + c0 + jj;
      Bs[bk][c0+jj] = (c < OD) ? Wp[(size_t)(kt+bk)*OD + c] : 0.0f;
    }
    __syncthreads();
#pragma unroll
    for (int kk = 0; kk < 16; ++kk){
      float4 a = *(const float4*)&As[kk][ty*4];
      float4 b = *(const float4*)&Bs[kk][tx*4];
      float aa[4]={a.x,a.y,a.z,a.w}, bb[4]={b.x,b.y,b.z,b.w};
#pragma unroll
      for (int ii=0; ii<4; ++ii)
#pragma unroll
        for (int jj=0; jj<4; ++jj) acc[ii][jj] += aa[ii]*bb[jj];
    }
    __syncthreads();
  }
#pragma unroll
  for (int ii=0; ii<4; ++ii){
    int r = bm*64 + ty*4 + ii;
#pragma unroll
    for (int jj=0; jj<4; ++jj){
      int c = bn*64 + tx*4 + jj;
      if (c < OD) out[(size_t)r*OD + c] = acc[ii][jj] + bp[c];
    }
  }
}

extern "C" void kernel_launch(void* const* d_in, const int* in_sizes, int n_in,
                              void* d_out, int out_size, void* d_ws, size_t ws_size,
                              hipStream_t stream){
  const float* fq = (const float*)d_in[0];
  const float* fk = (const float*)d_in[1];
  const float* fv = (const float*)d_in[2];
  const float* GA = (const float*)d_in[3];
  const float* GB = (const float*)d_in[4];
  const float* Wp = (const float*)d_in[5];
  const float* bp = (const float*)d_in[6];
  float* out  = (float*)d_out;
  float* attn = out + (size_t)S*OD;

  float* ws     = (float*)d_ws;
  float* QT     = ws;                                // 129*16384
  float* g      = QT + (size_t)129*N*N;              // 128*128
  float* bounds = g + (size_t)L*N;                   // 65*3*128
  float* cs     = bounds + (size_t)(NC+1)*3*N;       // 3*8192*128
  float* ctx    = cs + (size_t)3*S*N;                // 8192*128
  u16*   qkh    = (u16*)(ctx + (size_t)S*N);         // 2*S*N u16
  u16*   qkl    = qkh + (size_t)2*S*N;               // 2*S*N u16
  u16*   vth    = qkl + (size_t)2*S*N;               // S*N u16 (v hi, [N][S])
  u16*   vtl    = vth + (size_t)S*N;                 // S*N u16
  float* part   = (float*)(vtl + (size_t)S*N);       // 16*8192*128 (optional)
  size_t need_part = ((size_t)(part - ws) + (size_t)KSPLIT*S*N) * sizeof(float);
  bool use_part = (ws_size >= need_part);

  k_copyT<<<64, 256, 0, stream>>>(GA, QT + (size_t)N*N);
  for (int m = 1; m < L; m <<= 1)
    k_powmm<<<dim3(2,2,m), dim3(16,16), 0, stream>>>(QT, m);
  k_g<<<128, 128, 0, stream>>>(QT, GB, g);
  k_fill_local<<<dim3(4,3,NC), dim3(16,16), 0, stream>>>(fq, fk, fv, g, cs);
  k_bscan<<<1, 384, 0, stream>>>(QT, cs, bounds);
  k_fill_bound<<<dim3(L,4), 256, 0, stream>>>(QT, bounds, cs);

  // bf16 hi/lo splits of the scanned states
  k_split_qk<<<(2*S*N)/1024, 256, 0, stream>>>(cs, qkh, qkl);
  k_split_vT<<<S/64, 256, 0, stream>>>(cs + (size_t)2*S*N, vth, vtl);

  k_score_mfma<<<dim3(S/128, S/128), 256, 0, stream>>>(
      qkh, qkl, qkh + (size_t)S*N, qkl + (size_t)S*N, attn);
  k_softmax<<<S, 256, 0, stream>>>(attn);
  if (use_part){
    k_context_mfma<<<dim3(KSPLIT, S/128), 256, 0, stream>>>(attn, vth, vtl, part, 0);
    k_reduce<<<(S*N/4)/256, 256, 0, stream>>>(part, ctx);
  } else {
    hipMemsetAsync(ctx, 0, (size_t)S*N*sizeof(float), stream);
    k_context_mfma<<<dim3(KSPLIT, S/128), 256, 0, stream>>>(attn, vth, vtl, ctx, 1);
  }
  k_out<<<dim3(16, S/64), dim3(16,16), 0, stream>>>(ctx, Wp, bp, out);
}